// Round 9
// baseline (214.592 us; speedup 1.0000x reference)
//
#include <hip/hip_runtime.h>

#define SEQ 2048
#define NH 16
#define HD 64
#define DMODEL 1024

__device__ __forceinline__ unsigned int f2bf(float f) {
  // fp32 -> bf16 bits, round-to-nearest-even (finite inputs only)
  unsigned int u = __float_as_uint(f);
  return ((u + 0x7fffu + ((u >> 16) & 1u)) >> 16) & 0xffffu;
}

// packed fp32x2 -> bf16x2 (RNE via __bf16 cvt)
__device__ __forceinline__ unsigned int pk2bf(float a, float b) {
  unsigned short ua = __builtin_bit_cast(unsigned short, (__bf16)a);
  unsigned short ub = __builtin_bit_cast(unsigned short, (__bf16)b);
  return (unsigned int)ua | ((unsigned int)ub << 16);
}

typedef __bf16 bf16x8 __attribute__((ext_vector_type(8)));
typedef float f32x4 __attribute__((ext_vector_type(4)));
typedef unsigned int uix4 __attribute__((ext_vector_type(4)));
typedef unsigned int uix2 __attribute__((ext_vector_type(2)));

// async global->LDS, 16B per lane; LDS dest = wave-uniform base + lane*16
__device__ __forceinline__ void gl2lds16(const unsigned short* g, unsigned short* l) {
  __builtin_amdgcn_global_load_lds(
      (const __attribute__((address_space(1))) unsigned int*)g,
      (__attribute__((address_space(3))) unsigned int*)l, 16, 0, 0);
}

// cvt 8 fp32 (two float4) -> bf16x8 and store to LDS (16B, RNE — bit-identical
// to the old standalone cast kernel, so outputs are unchanged)
__device__ __forceinline__ void cvt_write8(float4 a, float4 b, unsigned short* lds) {
  uix4 o;
  o.x = pk2bf(a.x, a.y); o.y = pk2bf(a.z, a.w);
  o.z = pk2bf(b.x, b.y); o.w = pk2bf(b.z, b.w);
  *reinterpret_cast<uix4*>(lds) = o;
}

// ---------------------------------------------------------------------------
// ROUND 9: cast kernel ELIMINATED (4 kernels -> 3). Budget analysis: measured
// kernels (attn ~49, gemm0 ~45-58) never summed to the ~195 total; cast +
// gemm1 + launch gaps ~= 90 us. The GEMM loops are barrier-bound with idle
// VALU (14%), so fp32->bf16 conversion is folded into LDS staging for free:
// gemm_qkv reg-stages A (x fp32) AND B (Wq/Wk/Wv fp32) with pk2bf during the
// ds_write; gemm_out keeps proven DMA for A (cb bf16) and reg-stages B (Wo).
// Removes: 1 launch, cast's ~48 MB traffic, the xb/wb write->read round trip.
// Swizzle geometry identical to the proven kernels: global source column
// pre-swizzled (chunk = (lane&7)^(row&7)), LDS write at physical chunk
// (lane&7), frag read XORs with fx=fr&7 (rule #21 both-sides discipline).
// ---------------------------------------------------------------------------

// 128x128-tile fused QKV GEMM, K=1024, single-buffer LDS (32 KB), fp32 inputs.
// Grid (24, 32): n-segments 0..2 select Wq/Wk/Wv (per-block uniform).
__global__ __launch_bounds__(256) void gemm_qkv(
    const float* __restrict__ X, const float* __restrict__ Wq,
    const float* __restrict__ Wk, const float* __restrict__ Wv,
    const float* __restrict__ bq, const float* __restrict__ bk,
    const float* __restrict__ bv,
    unsigned short* __restrict__ Qo, unsigned short* __restrict__ Ko,
    unsigned short* __restrict__ Vto) {
  __shared__ __align__(16) unsigned short As[128 * 64];
  __shared__ __align__(16) unsigned short Bs[128 * 64];
  const int tid = threadIdx.x;
  const int wave = tid >> 6, lane = tid & 63;
  const int wm = wave >> 1, wn = wave & 1;  // 2x2 waves -> 64x64 sub-tiles
  const int fr = lane & 15, quad = lane >> 4;
  const int fx = fr & 7;  // swizzle key for fragment reads
  const int n0 = blockIdx.x * 128, m0 = blockIdx.y * 128;
  const int seg = n0 >> 10;  // uniform per block (128-col tile never crosses)
  const float* W = (seg == 0) ? Wq : (seg == 1) ? Wk : Wv;
  const float* bp = (seg == 0) ? bq : (seg == 1) ? bk : bv;

  // staging: lane -> (row = lane>>3, src chunk = (lane&7)^(row&7), LDS chunk
  // = lane&7). Each wave stages rows [wave*32, wave*32+32) via t = 0..3.
  const int sr = lane >> 3;
  const int sch = (lane & 7) ^ (sr & 7);
  const float* Ag = X + (size_t)(m0 + wave * 32 + sr) * 1024 + sch * 8;
  const float* Bg = W + (size_t)((n0 & 1023) + wave * 32 + sr) * 1024 + sch * 8;
  unsigned short* AsW = As + (wave * 32 + sr) * 64 + (lane & 7) * 8;
  unsigned short* BsW = Bs + (wave * 32 + sr) * 64 + (lane & 7) * 8;

  f32x4 acc[4][4];
#pragma unroll
  for (int mt = 0; mt < 4; ++mt)
#pragma unroll
    for (int nt = 0; nt < 4; ++nt) acc[mt][nt] = f32x4{0.f, 0.f, 0.f, 0.f};

  for (int k0 = 0; k0 < 1024; k0 += 64) {
    // A loads issue before the barrier: latency overlaps the compute-drain wait
    float4 ra[4][2];
#pragma unroll
    for (int t = 0; t < 4; ++t) {
      const float* g = Ag + (size_t)(t * 8) * 1024 + k0;
      ra[t][0] = *reinterpret_cast<const float4*>(g);
      ra[t][1] = *reinterpret_cast<const float4*>(g + 4);
    }
    __syncthreads();  // previous K-step's compute done: LDS safe to overwrite
#pragma unroll
    for (int t = 0; t < 4; ++t) cvt_write8(ra[t][0], ra[t][1], AsW + t * 8 * 64);
    {
      float4 rb[4][2];
#pragma unroll
      for (int t = 0; t < 4; ++t) {
        const float* g = Bg + (size_t)(t * 8) * 1024 + k0;
        rb[t][0] = *reinterpret_cast<const float4*>(g);
        rb[t][1] = *reinterpret_cast<const float4*>(g + 4);
      }
#pragma unroll
      for (int t = 0; t < 4; ++t) cvt_write8(rb[t][0], rb[t][1], BsW + t * 8 * 64);
    }
    __syncthreads();  // staged tile visible
#pragma unroll
    for (int ks = 0; ks < 2; ++ks) {
      bf16x8 af[4], bfv[4];
#pragma unroll
      for (int mt = 0; mt < 4; ++mt)
        af[mt] = *reinterpret_cast<const bf16x8*>(
            As + (wm * 64 + mt * 16 + fr) * 64 + ((ks * 4 + quad) ^ fx) * 8);
#pragma unroll
      for (int nt = 0; nt < 4; ++nt)
        bfv[nt] = *reinterpret_cast<const bf16x8*>(
            Bs + (wn * 64 + nt * 16 + fr) * 64 + ((ks * 4 + quad) ^ fx) * 8);
#pragma unroll
      for (int mt = 0; mt < 4; ++mt)
#pragma unroll
        for (int nt = 0; nt < 4; ++nt)
          acc[mt][nt] = __builtin_amdgcn_mfma_f32_16x16x32_bf16(
              af[mt], bfv[nt], acc[mt][nt], 0, 0, 0);
    }
  }

  // fused QKV epilogue (verbatim from the proven MODE-0 path).
  // C/D: col = lane&15, row = quad*4+reg (m89/m91-verified).
  // Q pre-scaled by (1/sqrt(64)) * log2(e): attention works in exp2 domain.
  const float scale = (seg == 0) ? 0.1803368809f : 1.0f;
  unsigned short* QK = (seg == 0) ? Qo : Ko;
#pragma unroll
  for (int nt = 0; nt < 4; ++nt) {
    const int c = (n0 + wn * 64 + nt * 16 + fr) & 1023;
    const int h = c >> 6, d = c & 63;
    const float bs = bp[c];
#pragma unroll
    for (int mt = 0; mt < 4; ++mt) {
      const int mbase = m0 + wm * 64 + mt * 16 + quad * 4;
      const int b = mbase >> 11, s0 = mbase & 2047;
      if (seg < 2) {
        unsigned short* dst = QK + (((size_t)(b * NH + h)) * SEQ + s0) * HD + d;
#pragma unroll
        for (int r = 0; r < 4; ++r)
          dst[(size_t)r * HD] = (unsigned short)f2bf((acc[mt][nt][r] + bs) * scale);
      } else {  // V^T: rows contiguous in s -> 8B store
        uint2 pk;
        pk.x = pk2bf(acc[mt][nt][0] + bs, acc[mt][nt][1] + bs);
        pk.y = pk2bf(acc[mt][nt][2] + bs, acc[mt][nt][3] + bs);
        *reinterpret_cast<uint2*>(
            Vto + (((size_t)(b * NH + h)) * HD + d) * SEQ + s0) = pk;
      }
    }
  }
}

// 64x128-tile out-projection GEMM: A = concat (bf16, proven DMA staging),
// B = Wo fp32 reg-staged with cast. fp32 C + bias. Grid (8, 64) = 512 blocks.
__global__ __launch_bounds__(256) void gemm_out(
    const unsigned short* __restrict__ A, const float* __restrict__ Wo,
    const float* __restrict__ bo, float* __restrict__ Cf) {
  __shared__ __align__(16) unsigned short As[64 * 64];
  __shared__ __align__(16) unsigned short Bs[128 * 64];
  const int tid = threadIdx.x;
  const int wave = tid >> 6, lane = tid & 63;
  const int wm = wave >> 1, wn = wave & 1;
  const int fr = lane & 15, quad = lane >> 4;
  const int fx = fr & 7;
  const int n0 = blockIdx.x * 128, m0 = blockIdx.y * 64;

  const int sr = lane >> 3;
  const int sch = (lane & 7) ^ (sr & 7);
  const unsigned short* Abase = A + (size_t)(m0 + wave * 16 + sr) * 1024 + sch * 8;
  const float* Bg = Wo + (size_t)(n0 + wave * 32 + sr) * 1024 + sch * 8;
  unsigned short* AsD = As + (wave * 16) * 64;  // DMA dest (wave-uniform base)
  unsigned short* BsW = Bs + (wave * 32 + sr) * 64 + (lane & 7) * 8;

  f32x4 acc[2][4];
#pragma unroll
  for (int mt = 0; mt < 2; ++mt)
#pragma unroll
    for (int nt = 0; nt < 4; ++nt) acc[mt][nt] = f32x4{0.f, 0.f, 0.f, 0.f};

  for (int k0 = 0; k0 < 1024; k0 += 64) {
    float4 rb[4][2];
#pragma unroll
    for (int t = 0; t < 4; ++t) {
      const float* g = Bg + (size_t)(t * 8) * 1024 + k0;
      rb[t][0] = *reinterpret_cast<const float4*>(g);
      rb[t][1] = *reinterpret_cast<const float4*>(g + 4);
    }
    __syncthreads();  // previous compute done: LDS safe to overwrite
#pragma unroll
    for (int t = 0; t < 2; ++t)
      gl2lds16(Abase + (size_t)(t * 8) * 1024 + k0, AsD + t * 8 * 64);
#pragma unroll
    for (int t = 0; t < 4; ++t) cvt_write8(rb[t][0], rb[t][1], BsW + t * 8 * 64);
    __syncthreads();  // drains DMA (vmcnt) + ds_writes: tile visible
#pragma unroll
    for (int ks = 0; ks < 2; ++ks) {
      bf16x8 af[2], bfv[4];
#pragma unroll
      for (int mt = 0; mt < 2; ++mt)
        af[mt] = *reinterpret_cast<const bf16x8*>(
            As + (wm * 32 + mt * 16 + fr) * 64 + ((ks * 4 + quad) ^ fx) * 8);
#pragma unroll
      for (int nt = 0; nt < 4; ++nt)
        bfv[nt] = *reinterpret_cast<const bf16x8*>(
            Bs + (wn * 64 + nt * 16 + fr) * 64 + ((ks * 4 + quad) ^ fx) * 8);
#pragma unroll
      for (int mt = 0; mt < 2; ++mt)
#pragma unroll
        for (int nt = 0; nt < 4; ++nt)
          acc[mt][nt] = __builtin_amdgcn_mfma_f32_16x16x32_bf16(
              af[mt], bfv[nt], acc[mt][nt], 0, 0, 0);
    }
  }

#pragma unroll
  for (int nt = 0; nt < 4; ++nt) {
    const int cg = n0 + wn * 64 + nt * 16 + fr;
    const float bs = bo[cg];
#pragma unroll
    for (int mt = 0; mt < 2; ++mt) {
      const int mbase = m0 + wm * 32 + mt * 16 + quad * 4;
#pragma unroll
      for (int r = 0; r < 4; ++r)
        Cf[(size_t)(mbase + r) * DMODEL + cg] = acc[mt][nt][r] + bs;
    }
  }
}

// MFMA flash attention, exp2 domain (round-4 proven version: 48.6-49.2 us;
// round-8 split REVERTED: occupancy 27->32% but dur +2us and +5us combine —
// partial-write traffic ate the tail reclaim). Single 64-row i-tile per
// block, grid 1024, 4 blocks/CU (LDS 32768 B). pi-permuted K rows -> P never
// touches LDS; stale-max softmax off the critical path; defer-8 rescale.
__global__ __launch_bounds__(256, 4) void attn_mfma_kernel(
    const unsigned short* __restrict__ Qg, const unsigned short* __restrict__ Kg,
    const unsigned short* __restrict__ Vtg, const int* __restrict__ mask,
    unsigned short* __restrict__ concat) {
  const int w = blockIdx.x >> 8;        // phase 0..3
  const int c = blockIdx.x & 255;
  const int gg = c >> 5;                // 0..7
  const int bh = c & 31;
  const int ib = (w == 0) ? (31 - gg) : (w == 1) ? gg : (w == 2) ? (23 - gg) : (8 + gg);
  const int b = bh >> 4, h = bh & 15;
  const int tid = threadIdx.x;
  const int wave = tid >> 6, lane = tid & 63;
  const int quad = lane >> 4, fr = lane & 15;
  const int fx = fr & 7;

  __shared__ __align__(16) unsigned short Ks[2][64 * 64];   // swizzled, pi-permuted rows
  __shared__ __align__(16) unsigned short Vts[2][64 * 64];  // swizzled, pitch 64

  const unsigned short* Qb = Qg + ((size_t)bh * SEQ) * HD;
  const unsigned short* Kb = Kg + ((size_t)bh * SEQ) * HD;
  const unsigned short* Vtb = Vtg + ((size_t)bh * HD) * SEQ;
  const int* maskb = mask + b * SEQ;

  bool badl = false;
  {
    const int4* mp4 = reinterpret_cast<const int4*>(maskb);
#pragma unroll
    for (int u = 0; u < 8; ++u) {
      int4 v = mp4[lane * 8 + u];
      badl |= !(v.x && v.y && v.z && v.w);
    }
  }
  const unsigned long long bm = __ballot(badl);

  const int ir = ib * 64 + wave * 16 + fr;  // this lane's Q row (softmax owner)
  const bf16x8 q0 = *reinterpret_cast<const bf16x8*>(Qb + (size_t)ir * HD + quad * 8);
  const bf16x8 q1 = *reinterpret_cast<const bf16x8*>(Qb + (size_t)ir * HD + quad * 8 + 32);
  const int padi = maskb[ir];

  f32x4 o[4];
#pragma unroll
  for (int vt = 0; vt < 4; ++vt) o[vt] = f32x4{0.f, 0.f, 0.f, 0.f};
  float mr = -1e20f;
  float lq = 0.f;

  const int srow8 = lane >> 3;
  const int sch8 = (lane & 7) ^ (srow8 & 7);
  const int kprow = (wave >> 1) * 32 + ((srow8 >> 2)) * 8 + (wave & 1) * 4 + (srow8 & 3);
  const unsigned short* Kcol = Kb + sch8 * 8;
  const unsigned short* Vsrc = Vtb + (size_t)(wave * 16 + srow8) * SEQ + sch8 * 8;
  const int cA0 = (quad ^ fx) * 8;
  const int cA1 = ((quad + 4) ^ fx) * 8;

  {
    unsigned short* KsW = Ks[0] + (wave * 16) * 64;
    unsigned short* VtsW = Vts[0] + (wave * 16) * 64;
#pragma unroll
    for (int t = 0; t < 2; ++t) {
      gl2lds16(Kcol + (size_t)(kprow + t * 16) * HD, KsW + t * 8 * 64);
      gl2lds16(Vsrc + (size_t)(t * 8) * SEQ, VtsW + t * 8 * 64);
    }
  }

  for (int jc = 0; jc <= ib; ++jc) {
    __syncthreads();
    if (jc < ib) {
      const int jn = (jc + 1) * 64;
      unsigned short* KsW = Ks[(jc + 1) & 1] + (wave * 16) * 64;
      unsigned short* VtsW = Vts[(jc + 1) & 1] + (wave * 16) * 64;
#pragma unroll
      for (int t = 0; t < 2; ++t) {
        gl2lds16(Kcol + (size_t)(jn + kprow + t * 16) * HD, KsW + t * 8 * 64);
        gl2lds16(Vsrc + (size_t)(t * 8) * SEQ + jn, VtsW + t * 8 * 64);
      }
    }
    const unsigned short* Kcur = Ks[jc & 1];
    const unsigned short* Vcur = Vts[jc & 1];
    const int j0 = jc * 64;
    const bool tb = ((bm >> (2 * jc)) & 3ull) != 0ull;

    f32x4 st[4];
    __builtin_amdgcn_s_setprio(1);
#pragma unroll
    for (int jt = 0; jt < 4; ++jt) {
      bf16x8 ka0 = *reinterpret_cast<const bf16x8*>(&Kcur[(jt * 16 + fr) * 64 + cA0]);
      bf16x8 ka1 = *reinterpret_cast<const bf16x8*>(&Kcur[(jt * 16 + fr) * 64 + cA1]);
      st[jt] = f32x4{0.f, 0.f, 0.f, 0.f};
      st[jt] = __builtin_amdgcn_mfma_f32_16x16x32_bf16(ka0, q0, st[jt], 0, 0, 0);
      st[jt] = __builtin_amdgcn_mfma_f32_16x16x32_bf16(ka1, q1, st[jt], 0, 0, 0);
    }
    __builtin_amdgcn_s_setprio(0);

    if (tb) {
      const int4* mp = reinterpret_cast<const int4*>(maskb + j0);
#pragma unroll
      for (int jt = 0; jt < 4; ++jt) {
        const int4 mv = mp[(jt >> 1) * 8 + quad * 2 + (jt & 1)];
        if (mv.x == 0) st[jt][0] = -1e30f;
        if (mv.y == 0) st[jt][1] = -1e30f;
        if (mv.z == 0) st[jt][2] = -1e30f;
        if (mv.w == 0) st[jt][3] = -1e30f;
      }
    }
    if (jc == ib) {
#pragma unroll
      for (int jt = 0; jt < 4; ++jt) {
        const int jb = j0 + (jt >> 1) * 32 + quad * 8 + (jt & 1) * 4;
#pragma unroll
        for (int r = 0; r < 4; ++r)
          if (jb + r > ir) st[jt][r] = -1e30f;
      }
    }

    float tmax = -1e30f;
#pragma unroll
    for (int jt = 0; jt < 4; ++jt)
#pragma unroll
      for (int r = 0; r < 4; ++r) tmax = fmaxf(tmax, st[jt][r]);
    tmax = fmaxf(tmax, __shfl_xor(tmax, 16));
    {
      uix2 rr = __builtin_amdgcn_permlane32_swap(__float_as_uint(tmax),
                                                 __float_as_uint(tmax), false, false);
      tmax = fmaxf(__uint_as_float(rr.x), __uint_as_float(rr.y));
    }
    if (jc == 0) mr = fmaxf(tmax, -1e20f);

    unsigned int pw[8];
#pragma unroll
    for (int jt = 0; jt < 4; ++jt) {
      float p0 = __builtin_amdgcn_exp2f(fminf(st[jt][0] - mr, 60.f));
      float p1 = __builtin_amdgcn_exp2f(fminf(st[jt][1] - mr, 60.f));
      float p2 = __builtin_amdgcn_exp2f(fminf(st[jt][2] - mr, 60.f));
      float p3 = __builtin_amdgcn_exp2f(fminf(st[jt][3] - mr, 60.f));
      lq += (p0 + p1) + (p2 + p3);
      pw[2 * jt] = pk2bf(p0, p1);
      pw[2 * jt + 1] = pk2bf(p2, p3);
    }
    const bf16x8 pa0 = __builtin_bit_cast(bf16x8, uix4{pw[0], pw[1], pw[2], pw[3]});
    const bf16x8 pa1 = __builtin_bit_cast(bf16x8, uix4{pw[4], pw[5], pw[6], pw[7]});

    __builtin_amdgcn_s_setprio(1);
#pragma unroll
    for (int vt = 0; vt < 4; ++vt) {
      bf16x8 vb0 = *reinterpret_cast<const bf16x8*>(&Vcur[(vt * 16 + fr) * 64 + cA0]);
      bf16x8 vb1 = *reinterpret_cast<const bf16x8*>(&Vcur[(vt * 16 + fr) * 64 + cA1]);
      o[vt] = __builtin_amdgcn_mfma_f32_16x16x32_bf16(vb0, pa0, o[vt], 0, 0, 0);
      o[vt] = __builtin_amdgcn_mfma_f32_16x16x32_bf16(vb1, pa1, o[vt], 0, 0, 0);
    }
    __builtin_amdgcn_s_setprio(0);

    if (jc > 0) {
      const bool upd = __ballot(tmax > mr + 8.f) != 0ull;
      if (upd) {
        const float mn = fmaxf(mr, tmax);
        const float corr = __builtin_amdgcn_exp2f(mr - mn);
        mr = mn;
        lq *= corr;
#pragma unroll
        for (int vt = 0; vt < 4; ++vt) {
          o[vt][0] *= corr; o[vt][1] *= corr; o[vt][2] *= corr; o[vt][3] *= corr;
        }
      }
    }
  }

  float lr = lq;
  lr += __shfl_xor(lr, 16);
  lr += __shfl_xor(lr, 32);
  const float inv = (padi != 0 && lr > 0.f) ? 1.f / lr : 0.f;
  unsigned short* orow = concat + ((size_t)(b * SEQ + ir)) * DMODEL + h * HD;
#pragma unroll
  for (int vt = 0; vt < 4; ++vt) {
    uint2 pk;
    pk.x = pk2bf(o[vt][0] * inv, o[vt][1] * inv);
    pk.y = pk2bf(o[vt][2] * inv, o[vt][3] * inv);
    *reinterpret_cast<uint2*>(orow + vt * 16 + quad * 4) = pk;
  }
}

extern "C" void kernel_launch(void* const* d_in, const int* in_sizes, int n_in,
                              void* d_out, int out_size, void* d_ws, size_t ws_size,
                              hipStream_t stream) {
  (void)in_sizes; (void)n_in; (void)out_size;
  const float* x  = (const float*)d_in[0];
  const int* mask = (const int*)d_in[1];
  const float* Wq = (const float*)d_in[2];
  const float* bq = (const float*)d_in[3];
  const float* Wk = (const float*)d_in[4];
  const float* bk = (const float*)d_in[5];
  const float* Wv = (const float*)d_in[6];
  const float* bv = (const float*)d_in[7];
  const float* Wo = (const float*)d_in[8];
  const float* bo = (const float*)d_in[9];
  float* out = (float*)d_out;

  char* ws = (char*)d_ws;
  if (ws_size < (48ull << 20)) return;
  unsigned short* Qb  = (unsigned short*)(ws + (16ull << 20)); // 8 MB [b,h,s,64] (xscale)
  unsigned short* Kb  = (unsigned short*)(ws + (24ull << 20)); // 8 MB [b,h,s,64]
  unsigned short* Vtb = (unsigned short*)(ws + (32ull << 20)); // 8 MB [b,h,64,s]
  unsigned short* cb  = (unsigned short*)(ws + (40ull << 20)); // 8 MB concat bf16

  // fused QKV projection straight from fp32 inputs (cast folded into staging)
  gemm_qkv<<<dim3(24, 32), 256, 0, stream>>>(x, Wq, Wk, Wv, bq, bk, bv,
                                             Qb, Kb, Vtb);

  attn_mfma_kernel<<<1024, 256, 0, stream>>>(Qb, Kb, Vtb, mask, cb);

  // out projection straight from fp32 Wo (cast folded into staging)
  gemm_out<<<dim3(8, 64), 256, 0, stream>>>(cb, Wo, bo, out);
}

// Round 10
// 185.477 us; speedup vs baseline: 1.1570x; 1.1570x over previous
//
#include <hip/hip_runtime.h>

#define SEQ 2048
#define NH 16
#define HD 64
#define DMODEL 1024

__device__ __forceinline__ unsigned int f2bf(float f) {
  // fp32 -> bf16 bits, round-to-nearest-even (finite inputs only)
  unsigned int u = __float_as_uint(f);
  return ((u + 0x7fffu + ((u >> 16) & 1u)) >> 16) & 0xffffu;
}

// packed fp32x2 -> bf16x2 (RNE via __bf16 cvt)
__device__ __forceinline__ unsigned int pk2bf(float a, float b) {
  unsigned short ua = __builtin_bit_cast(unsigned short, (__bf16)a);
  unsigned short ub = __builtin_bit_cast(unsigned short, (__bf16)b);
  return (unsigned int)ua | ((unsigned int)ub << 16);
}

typedef __bf16 bf16x8 __attribute__((ext_vector_type(8)));
typedef float f32x4 __attribute__((ext_vector_type(4)));
typedef unsigned int uix4 __attribute__((ext_vector_type(4)));
typedef unsigned int uix2 __attribute__((ext_vector_type(2)));

// async global->LDS, 16B per lane; LDS dest = wave-uniform base + lane*16
__device__ __forceinline__ void gl2lds16(const unsigned short* g, unsigned short* l) {
  __builtin_amdgcn_global_load_lds(
      (const __attribute__((address_space(1))) unsigned int*)g,
      (__attribute__((address_space(3))) unsigned int*)l, 16, 0, 0);
}

// one launch casts x + all four weight matrices to bf16
__global__ __launch_bounds__(256) void cast_all_kernel(
    const float* __restrict__ x, const float* __restrict__ wq,
    const float* __restrict__ wk, const float* __restrict__ wv,
    const float* __restrict__ wo,
    unsigned short* __restrict__ xb, unsigned short* __restrict__ wqb,
    unsigned short* __restrict__ wkb, unsigned short* __restrict__ wvb,
    unsigned short* __restrict__ wob) {
  int idx = blockIdx.x * 256 + threadIdx.x;
  if (idx >= 1048576) return;
  const float* src;
  unsigned short* dst;
  int off;
  if (idx < 524288) {
    src = x; dst = xb; off = idx;
  } else {
    int t = idx - 524288;
    int w = t >> 17;
    off = t & 131071;
    src = (w == 0) ? wq : (w == 1) ? wk : (w == 2) ? wv : wo;
    dst = (w == 0) ? wqb : (w == 1) ? wkb : (w == 2) ? wvb : wob;
  }
  const float4* p = reinterpret_cast<const float4*>(src) + (size_t)off * 2;
  float4 a = p[0], b = p[1];
  uint4 o;
  o.x = f2bf(a.x) | (f2bf(a.y) << 16);
  o.y = f2bf(a.z) | (f2bf(a.w) << 16);
  o.z = f2bf(b.x) | (f2bf(b.y) << 16);
  o.w = f2bf(b.z) | (f2bf(b.w) << 16);
  reinterpret_cast<uint4*>(dst)[off] = o;
}

// TM x 128-tile GEMM, BK=64, global_load_lds staging, XOR-swizzled LDS chunks.
// Single-buffered, 2 barriers per K-step; at 32 KB LDS this runs 5 blocks/CU
// and cross-block co-residency hides the staging latency (measured: dbuf and
// 8-phase variants were equal or worse at this shape — r4/r6 ERRATA).
// MODE 0: fused QKV epilogue (cols 0..1023 Q *qscale, 1024..2047 K, 2048..3071 V^T).
// MODE 1: fp32 C[M][1024] + bias0 (out projection).
// TM in {64,128}: 64-row tiles double the grid for small shapes (out-proj:
// TM=64 -> 512 blocks = 2/CU instead of 1/CU).
template <int MODE, int TM>
__global__ __launch_bounds__(256) void gemm128(
    const unsigned short* __restrict__ A, const unsigned short* __restrict__ B,
    const float* __restrict__ bias0, const float* __restrict__ bias1,
    const float* __restrict__ bias2, float* __restrict__ Cf,
    unsigned short* __restrict__ Qo, unsigned short* __restrict__ Ko,
    unsigned short* __restrict__ Vto, int Kdim) {
  constexpr int MT = TM / 32;  // acc rows (16-row frags) per wave
  __shared__ __align__(16) unsigned short As[TM * 64];
  __shared__ __align__(16) unsigned short Bs[128 * 64];
  const int tid = threadIdx.x;
  const int wave = tid >> 6, lane = tid & 63;
  const int wm = wave >> 1, wn = wave & 1;  // 2x2 waves
  const int fr = lane & 15, quad = lane >> 4;
  const int fx = fr & 7;  // swizzle key for fragment reads
  const int n0 = blockIdx.x * 128, m0 = blockIdx.y * TM;

  // staging: lane -> (row = lane>>3, swizzled chunk = (lane&7) ^ ((lane>>3)&7))
  const int srowg = lane >> 3;
  const int schunk = (lane & 7) ^ (srowg & 7);
  const unsigned short* Abase =
      A + (size_t)(m0 + wave * (TM / 4) + srowg) * Kdim + schunk * 8;
  const unsigned short* Bbase =
      B + (size_t)(n0 + wave * 32 + srowg) * Kdim + schunk * 8;
  unsigned short* AsW = As + (wave * (TM / 4)) * 64;
  unsigned short* BsW = Bs + (wave * 32) * 64;

  f32x4 acc[MT][4];
#pragma unroll
  for (int mt = 0; mt < MT; ++mt)
#pragma unroll
    for (int nt = 0; nt < 4; ++nt) acc[mt][nt] = f32x4{0.f, 0.f, 0.f, 0.f};

  for (int k0 = 0; k0 < Kdim; k0 += 64) {
#pragma unroll
    for (int t = 0; t < TM / 32; ++t)
      gl2lds16(Abase + (size_t)(t * 8) * Kdim + k0, AsW + t * 8 * 64);
#pragma unroll
    for (int t = 0; t < 4; ++t)
      gl2lds16(Bbase + (size_t)(t * 8) * Kdim + k0, BsW + t * 8 * 64);
    __syncthreads();  // drains vmcnt(0): staged tile visible
#pragma unroll
    for (int ks = 0; ks < 2; ++ks) {
      bf16x8 af[MT], bfv[4];
#pragma unroll
      for (int mt = 0; mt < MT; ++mt)
        af[mt] = *reinterpret_cast<const bf16x8*>(
            As + (wm * (TM / 2) + mt * 16 + fr) * 64 + ((ks * 4 + quad) ^ fx) * 8);
#pragma unroll
      for (int nt = 0; nt < 4; ++nt)
        bfv[nt] = *reinterpret_cast<const bf16x8*>(
            Bs + (wn * 64 + nt * 16 + fr) * 64 + ((ks * 4 + quad) ^ fx) * 8);
#pragma unroll
      for (int mt = 0; mt < MT; ++mt)
#pragma unroll
        for (int nt = 0; nt < 4; ++nt)
          acc[mt][nt] = __builtin_amdgcn_mfma_f32_16x16x32_bf16(
              af[mt], bfv[nt], acc[mt][nt], 0, 0, 0);
    }
    __syncthreads();
  }

  // epilogue. C/D: col = lane&15, row = quad*4+reg (m89/m91-verified).
  if (MODE == 0) {
    const int seg = n0 >> 10;  // uniform per block
    const float* bp = (seg == 0) ? bias0 : (seg == 1) ? bias1 : bias2;
    // Q pre-scaled by (1/sqrt(64)) * log2(e): attention works in exp2 domain
    const float scale = (seg == 0) ? 0.1803368809f : 1.0f;
    unsigned short* QK = (seg == 0) ? Qo : Ko;
#pragma unroll
    for (int nt = 0; nt < 4; ++nt) {
      const int c = (n0 + wn * 64 + nt * 16 + fr) & 1023;
      const int h = c >> 6, d = c & 63;
      const float bs = bp[c];
#pragma unroll
      for (int mt = 0; mt < MT; ++mt) {
        const int mbase = m0 + wm * (TM / 2) + mt * 16 + quad * 4;
        const int b = mbase >> 11, s0 = mbase & 2047;
        if (seg < 2) {
          unsigned short* dst = QK + (((size_t)(b * NH + h)) * SEQ + s0) * HD + d;
#pragma unroll
          for (int r = 0; r < 4; ++r)
            dst[(size_t)r * HD] = (unsigned short)f2bf((acc[mt][nt][r] + bs) * scale);
        } else {  // V^T: rows contiguous in s -> 8B store
          uint2 pk;
          pk.x = pk2bf(acc[mt][nt][0] + bs, acc[mt][nt][1] + bs);
          pk.y = pk2bf(acc[mt][nt][2] + bs, acc[mt][nt][3] + bs);
          *reinterpret_cast<uint2*>(
              Vto + (((size_t)(b * NH + h)) * HD + d) * SEQ + s0) = pk;
        }
      }
    }
  } else {
#pragma unroll
    for (int nt = 0; nt < 4; ++nt) {
      const int cg = n0 + wn * 64 + nt * 16 + fr;
      const float bs = bias0[cg];
#pragma unroll
      for (int mt = 0; mt < MT; ++mt) {
        const int mbase = m0 + wm * (TM / 2) + mt * 16 + quad * 4;
#pragma unroll
        for (int r = 0; r < 4; ++r)
          Cf[(size_t)(mbase + r) * DMODEL + cg] = acc[mt][nt][r] + bs;
      }
    }
  }
}

// MFMA flash attention, exp2 domain. Single 64-row i-tile per block, grid 1024,
// 4 blocks/CU resident (LDS 32768 B). Dispatch-class balance: every stride-256
// class sums to 62 tile-passes.
// K-tile ROWS are permuted at DMA time with the bit permutation pi(m) =
// m5*32 + m[3:2]*8 + m4*4 + m[1:0]. With this pi, the S^T=K*Q^T output row m
// scores column j0+pi(m), and each lane's own st[jt][r] values ARE the PV
// B-fragment (B[k=quad*8+e] <-> jt=2S+(e>>2), r=e&3). P therefore never
// touches LDS: pack exp2 results into bf16x8 regs and feed V^T*P^T directly.
// (Best-measured config: this exact kernel benched 49.0 us / 187.8 total.)
__global__ __launch_bounds__(256, 4) void attn_mfma_kernel(
    const unsigned short* __restrict__ Qg, const unsigned short* __restrict__ Kg,
    const unsigned short* __restrict__ Vtg, const int* __restrict__ mask,
    unsigned short* __restrict__ concat) {
  const int w = blockIdx.x >> 8;        // phase 0..3
  const int c = blockIdx.x & 255;
  const int gg = c >> 5;                // 0..7
  const int bh = c & 31;
  const int ib = (w == 0) ? (31 - gg) : (w == 1) ? gg : (w == 2) ? (23 - gg) : (8 + gg);
  const int b = bh >> 4, h = bh & 15;
  const int tid = threadIdx.x;
  const int wave = tid >> 6, lane = tid & 63;
  const int quad = lane >> 4, fr = lane & 15;
  const int fx = fr & 7;

  __shared__ __align__(16) unsigned short Ks[2][64 * 64];   // swizzled, pitch 64, pi-permuted rows
  __shared__ __align__(16) unsigned short Vts[2][64 * 64];  // swizzled, pitch 64

  const unsigned short* Qb = Qg + ((size_t)bh * SEQ) * HD;
  const unsigned short* Kb = Kg + ((size_t)bh * SEQ) * HD;
  const unsigned short* Vtb = Vtg + ((size_t)bh * HD) * SEQ;
  const int* maskb = mask + b * SEQ;

  // pad-mask tile bitmap via wave ballot: lane covers ints [lane*32, lane*32+32)
  // -> tile jc covered by ballot bits {2jc, 2jc+1}
  bool badl = false;
  {
    const int4* mp4 = reinterpret_cast<const int4*>(maskb);
#pragma unroll
    for (int u = 0; u < 8; ++u) {
      int4 v = mp4[lane * 8 + u];
      badl |= !(v.x && v.y && v.z && v.w);
    }
  }
  const unsigned long long bm = __ballot(badl);

  const int ir = ib * 64 + wave * 16 + fr;  // this lane's Q row (softmax owner)
  const bf16x8 q0 = *reinterpret_cast<const bf16x8*>(Qb + (size_t)ir * HD + quad * 8);
  const bf16x8 q1 = *reinterpret_cast<const bf16x8*>(Qb + (size_t)ir * HD + quad * 8 + 32);
  const int padi = maskb[ir];

  f32x4 o[4];
#pragma unroll
  for (int vt = 0; vt < 4; ++vt) o[vt] = f32x4{0.f, 0.f, 0.f, 0.f};
  // init -1e20 (not -1e30): all-masked tiles then give exp2(-1e30+1e20)=0 safely
  float mr = -1e20f;
  float lq = 0.f;  // per-quad partial row-sum; cross-quad reduced in epilogue

  // staging: wave stages LDS rows [wave*16, wave*16+16) of K and V^T tiles,
  // 2 DMA calls each. lane -> (ldsrow = lane>>3, physchunk = lane&7,
  // logical chunk = (lane&7)^(ldsrow&7)).
  // K rows permuted: global row for LDS row m = j0 + pi(m); with
  // m = wave*16 + t*8 + srow8: pi = (wave>>1)*32 + t*16 + (srow8>>2)*8
  //                                 + (wave&1)*4 + (srow8&3).
  const int srow8 = lane >> 3;
  const int sch8 = (lane & 7) ^ (srow8 & 7);
  const int kprow = (wave >> 1) * 32 + ((srow8 >> 2)) * 8 + (wave & 1) * 4 + (srow8 & 3);
  const unsigned short* Kcol = Kb + sch8 * 8;
  const unsigned short* Vsrc = Vtb + (size_t)(wave * 16 + srow8) * SEQ + sch8 * 8;
  const int cA0 = (quad ^ fx) * 8;        // frag chunk for k in [0,32)
  const int cA1 = ((quad + 4) ^ fx) * 8;  // frag chunk for k in [32,64)

  // pre-issue DMA for jc=0 into buffer 0
  {
    unsigned short* KsW = Ks[0] + (wave * 16) * 64;
    unsigned short* VtsW = Vts[0] + (wave * 16) * 64;
#pragma unroll
    for (int t = 0; t < 2; ++t) {
      gl2lds16(Kcol + (size_t)(kprow + t * 16) * HD, KsW + t * 8 * 64);
      gl2lds16(Vsrc + (size_t)(t * 8) * SEQ, VtsW + t * 8 * 64);
    }
  }

  for (int jc = 0; jc <= ib; ++jc) {
    __syncthreads();  // drains DMA[jc] (vmcnt) + guards buffer reuse
    if (jc < ib) {    // prefetch next tile into the other buffer
      const int jn = (jc + 1) * 64;
      unsigned short* KsW = Ks[(jc + 1) & 1] + (wave * 16) * 64;
      unsigned short* VtsW = Vts[(jc + 1) & 1] + (wave * 16) * 64;
#pragma unroll
      for (int t = 0; t < 2; ++t) {
        gl2lds16(Kcol + (size_t)(jn + kprow + t * 16) * HD, KsW + t * 8 * 64);
        gl2lds16(Vsrc + (size_t)(t * 8) * SEQ + jn, VtsW + t * 8 * 64);
      }
    }
    const unsigned short* Kcur = Ks[jc & 1];
    const unsigned short* Vcur = Vts[jc & 1];
    const int j0 = jc * 64;
    const bool tb = ((bm >> (2 * jc)) & 3ull) != 0ull;

    // S^T strip: C[m][n=i=fr]; row m holds score for column j0 + pi(m)
    f32x4 st[4];
    __builtin_amdgcn_s_setprio(1);
#pragma unroll
    for (int jt = 0; jt < 4; ++jt) {
      bf16x8 ka0 = *reinterpret_cast<const bf16x8*>(&Kcur[(jt * 16 + fr) * 64 + cA0]);
      bf16x8 ka1 = *reinterpret_cast<const bf16x8*>(&Kcur[(jt * 16 + fr) * 64 + cA1]);
      st[jt] = f32x4{0.f, 0.f, 0.f, 0.f};
      st[jt] = __builtin_amdgcn_mfma_f32_16x16x32_bf16(ka0, q0, st[jt], 0, 0, 0);
      st[jt] = __builtin_amdgcn_mfma_f32_16x16x32_bf16(ka1, q1, st[jt], 0, 0, 0);
    }
    __builtin_amdgcn_s_setprio(0);

    // lane (quad,fr) reg (jt,r) holds score for column j0 + pjb(jt,quad) + r,
    // pjb = (jt>>1)*32 + quad*8 + (jt&1)*4   (the pi permutation)
    if (tb) {  // rare: per-element pad-col mask
      const int4* mp = reinterpret_cast<const int4*>(maskb + j0);
#pragma unroll
      for (int jt = 0; jt < 4; ++jt) {
        const int4 mv = mp[(jt >> 1) * 8 + quad * 2 + (jt & 1)];
        if (mv.x == 0) st[jt][0] = -1e30f;
        if (mv.y == 0) st[jt][1] = -1e30f;
        if (mv.z == 0) st[jt][2] = -1e30f;
        if (mv.w == 0) st[jt][3] = -1e30f;
      }
    }
    if (jc == ib) {  // diagonal tile: causal mask (pi-permuted columns)
#pragma unroll
      for (int jt = 0; jt < 4; ++jt) {
        const int jb = j0 + (jt >> 1) * 32 + quad * 8 + (jt & 1) * 4;
#pragma unroll
        for (int r = 0; r < 4; ++r)
          if (jb + r > ir) st[jt][r] = -1e30f;
      }
    }

    // online softmax for row i=fr (max replicated across quads)
    float tmax = -1e30f;
#pragma unroll
    for (int jt = 0; jt < 4; ++jt)
#pragma unroll
      for (int r = 0; r < 4; ++r) tmax = fmaxf(tmax, st[jt][r]);
    tmax = fmaxf(tmax, __shfl_xor(tmax, 16));
    {  // lane^32 max via permlane32_swap (VALU, no DS round-trip)
      uix2 rr = __builtin_amdgcn_permlane32_swap(__float_as_uint(tmax),
                                                 __float_as_uint(tmax), false, false);
      tmax = fmaxf(__uint_as_float(rr.x), __uint_as_float(rr.y));
    }
    // defer-max (T13): skip rescale unless some row grows by > 8 (exp2 domain)
    const bool upd = __ballot(tmax > mr + 8.f) != 0ull;  // wave-uniform
    if (upd) {
      const float mn = fmaxf(mr, tmax);
      const float corr = __builtin_amdgcn_exp2f(mr - mn);
      mr = mn;
      lq *= corr;
#pragma unroll
      for (int vt = 0; vt < 4; ++vt) {
        o[vt][0] *= corr; o[vt][1] *= corr; o[vt][2] *= corr; o[vt][3] *= corr;
      }
    }
    unsigned int pw[8];
#pragma unroll
    for (int jt = 0; jt < 4; ++jt) {
      float p0 = __builtin_amdgcn_exp2f(st[jt][0] - mr);
      float p1 = __builtin_amdgcn_exp2f(st[jt][1] - mr);
      float p2 = __builtin_amdgcn_exp2f(st[jt][2] - mr);
      float p3 = __builtin_amdgcn_exp2f(st[jt][3] - mr);
      lq += (p0 + p1) + (p2 + p3);
      pw[2 * jt] = pk2bf(p0, p1);
      pw[2 * jt + 1] = pk2bf(p2, p3);
    }
    // PV B-fragments directly from own registers (pi made ownership line up):
    // pa0 = [st0.p0..p3, st1.p0..p3], pa1 = [st2.p0..p3, st3.p0..p3]
    const bf16x8 pa0 = __builtin_bit_cast(bf16x8, uix4{pw[0], pw[1], pw[2], pw[3]});
    const bf16x8 pa1 = __builtin_bit_cast(bf16x8, uix4{pw[4], pw[5], pw[6], pw[7]});

    // O^T += V^T * P^T
    __builtin_amdgcn_s_setprio(1);
#pragma unroll
    for (int vt = 0; vt < 4; ++vt) {
      bf16x8 vb0 = *reinterpret_cast<const bf16x8*>(&Vcur[(vt * 16 + fr) * 64 + cA0]);
      bf16x8 vb1 = *reinterpret_cast<const bf16x8*>(&Vcur[(vt * 16 + fr) * 64 + cA1]);
      o[vt] = __builtin_amdgcn_mfma_f32_16x16x32_bf16(vb0, pa0, o[vt], 0, 0, 0);
      o[vt] = __builtin_amdgcn_mfma_f32_16x16x32_bf16(vb1, pa1, o[vt], 0, 0, 0);
    }
    __builtin_amdgcn_s_setprio(0);
  }

  // epilogue: cross-quad l reduction (deferred from loop), then O^T / l
  float lr = lq;
  lr += __shfl_xor(lr, 16);
  lr += __shfl_xor(lr, 32);
  const float inv = (padi != 0 && lr > 0.f) ? 1.f / lr : 0.f;
  unsigned short* orow = concat + ((size_t)(b * SEQ + ir)) * DMODEL + h * HD;
#pragma unroll
  for (int vt = 0; vt < 4; ++vt) {
    uint2 pk;
    pk.x = pk2bf(o[vt][0] * inv, o[vt][1] * inv);
    pk.y = pk2bf(o[vt][2] * inv, o[vt][3] * inv);
    *reinterpret_cast<uint2*>(orow + vt * 16 + quad * 4) = pk;
  }
}

extern "C" void kernel_launch(void* const* d_in, const int* in_sizes, int n_in,
                              void* d_out, int out_size, void* d_ws, size_t ws_size,
                              hipStream_t stream) {
  (void)in_sizes; (void)n_in; (void)out_size;
  const float* x  = (const float*)d_in[0];
  const int* mask = (const int*)d_in[1];
  const float* Wq = (const float*)d_in[2];
  const float* bq = (const float*)d_in[3];
  const float* Wk = (const float*)d_in[4];
  const float* bk = (const float*)d_in[5];
  const float* Wv = (const float*)d_in[6];
  const float* bv = (const float*)d_in[7];
  const float* Wo = (const float*)d_in[8];
  const float* bo = (const float*)d_in[9];
  float* out = (float*)d_out;

  char* ws = (char*)d_ws;
  if (ws_size < (48ull << 20)) return;
  unsigned short* xb  = (unsigned short*)(ws);                 // 8 MB x bf16 [4096][1024]
  unsigned short* wqb = (unsigned short*)(ws + (8ull  << 20)); // wq|wk|wv contiguous ->
  unsigned short* wkb = (unsigned short*)(ws + (10ull << 20)); //   [3072][1024] B matrix
  unsigned short* wvb = (unsigned short*)(ws + (12ull << 20));
  unsigned short* wob = (unsigned short*)(ws + (14ull << 20));
  unsigned short* Qb  = (unsigned short*)(ws + (16ull << 20)); // 8 MB [b,h,s,64] (xscale)
  unsigned short* Kb  = (unsigned short*)(ws + (24ull << 20)); // 8 MB [b,h,s,64]
  unsigned short* Vtb = (unsigned short*)(ws + (32ull << 20)); // 8 MB [b,h,64,s]
  unsigned short* cb  = (unsigned short*)(ws + (40ull << 20)); // 8 MB concat bf16

  cast_all_kernel<<<4096, 256, 0, stream>>>(x, Wq, Wk, Wv, Wo, xb, wqb, wkb, wvb, wob);

  // fused QKV projection: B = [wq; wk; wv] = [3072][1024]
  gemm128<0, 128><<<dim3(24, 32), 256, 0, stream>>>(xb, wqb, bq, bk, bv,
                                                    nullptr, Qb, Kb, Vtb, 1024);

  attn_mfma_kernel<<<1024, 256, 0, stream>>>(Qb, Kb, Vtb, mask, cb);

  // out projection: 64-row M-tiles -> 512 blocks (2/CU)
  gemm128<1, 64><<<dim3(8, 64), 256, 0, stream>>>(cb, wob, bo, nullptr, nullptr,
                                                  out, nullptr, nullptr, nullptr, 1024);
}